// Round 3
// baseline (234.367 us; speedup 1.0000x reference)
//
#include <hip/hip_runtime.h>
#include <hip/hip_fp16.h>

// LightGCN on MI355X. Gather formulation, dinv folded into data (y = dinv*x,
// fp16 128B rows). CSR built via LDS-staged two-phase binning (wave-scan based).
// Gather v3: 8 lanes per node, 8 nodes per wave; per 8-edge block ALL 8 row
// loads are issued back-to-back (branchless via a zero row at index kNodes for
// padding slots) -> 8 outstanding 128B loads per group for latency hiding.
// Inner accumulate via v_fma_mix_f32 (fp16 -> fp32 accumulate in 1 VALU op).
// Layers 1-2 write only y (19.2MB). Layer 3 reconstructs h1,h2 from y1,y2
// (h = y * sqrt(deg)) and writes out = (emb + h1 + h2 + h3)/4.
// prescale (y0 = fp16(dinv*emb)) is fused into the tail of binB.
//
// d_in[0]: edge_index int32 [2][1M]; d_in[1]: emb_weight fp32 [150000][64]
// d_out  : 150000x64 fp32

constexpr int kNodes     = 150000;
constexpr int kDim       = 64;
constexpr int kEdges     = 1000000;
constexpr int kEmbFloats = kNodes * kDim;            // 9,600,000
constexpr int kBkt       = (kNodes + 255) / 256;     // 586 buckets
constexpr int kBktCap    = 2048;                     // mean 1707, +8.3 sigma
constexpr int kChunk     = 4096;                     // edges per binA block

typedef float  floatx4 __attribute__((ext_vector_type(4)));

__device__ __forceinline__ int wave_incl_scan(int v, int lane) {
    #pragma unroll
    for (int s = 1; s < 64; s <<= 1) {
        int u = __shfl_up(v, s);
        if (lane >= s) v += u;
    }
    return v;
}

// fp16 (packed in int bits) accumulated into fp32 in one VALU op.
#define ACC_LO(s, r) asm("v_fma_mix_f32 %0, %1, 1.0, %0 op_sel:[0,0,0] op_sel_hi:[1,0,0]" : "+v"(s) : "v"(r))
#define ACC_HI(s, r) asm("v_fma_mix_f32 %0, %1, 1.0, %0 op_sel:[1,0,0] op_sel_hi:[1,0,0]" : "+v"(s) : "v"(r))

#define ACC_ROW(rr) do { \
    ACC_LO(s0, rr.x); ACC_HI(s1, rr.x); \
    ACC_LO(s2, rr.y); ACC_HI(s3, rr.y); \
    ACC_LO(s4, rr.z); ACC_HI(s5, rr.z); \
    ACC_LO(s6, rr.w); ACC_HI(s7, rr.w); } while (0)

// ---------------- Phase A: bin edges by dst>>8, LDS-staged ----------------

__global__ __launch_bounds__(1024) void binA_kernel(const int* __restrict__ src,
                                                    const int* __restrict__ dst,
                                                    int* __restrict__ cur,     // [kBkt] zeroed
                                                    unsigned* __restrict__ bin) {
    __shared__ int hist[1024];
    __shared__ int cursor[1024];
    __shared__ int sexcl[1024];
    __shared__ int gstart[1024];
    __shared__ int wsum[16];
    __shared__ unsigned staged[kChunk];
    __shared__ unsigned short sbkt[kChunk];

    int t      = threadIdx.x;
    int lane   = t & 63;
    int w      = t >> 6;
    int chunk0 = blockIdx.x * kChunk;
    int n      = min(kChunk, kEdges - chunk0);

    hist[t] = 0;
    __syncthreads();

    int myb[4], myd[4];
    #pragma unroll
    for (int j = 0; j < 4; ++j) {
        int i = j * 1024 + t;
        if (i < n) {
            int d = dst[chunk0 + i];
            myb[j] = d >> 8;
            myd[j] = d & 255;
            atomicAdd(&hist[myb[j]], 1);
        } else myb[j] = -1;
    }
    __syncthreads();

    // exclusive scan of hist[0..1023] via wave scans
    int c   = hist[t];
    int inc = wave_incl_scan(c, lane);
    if (lane == 63) wsum[w] = inc;
    __syncthreads();
    if (w == 0) {
        int v  = (lane < 16) ? wsum[lane] : 0;
        int sc = wave_incl_scan(v, lane);
        if (lane < 16) wsum[lane] = sc - v;   // exclusive wave offsets
    }
    __syncthreads();
    int excl = wsum[w] + inc - c;
    sexcl[t]  = excl;
    cursor[t] = excl;
    if (t < kBkt) gstart[t] = atomicAdd(&cur[t], c);
    __syncthreads();

    // place into LDS ordered by bucket
    #pragma unroll
    for (int j = 0; j < 4; ++j) {
        int i = j * 1024 + t;
        if (i < n) {
            int s = src[chunk0 + i];
            unsigned pk = ((unsigned)myd[j] << 24) | (unsigned)s;
            int p = atomicAdd(&cursor[myb[j]], 1);
            staged[p] = pk;
            sbkt[p]   = (unsigned short)myb[j];
        }
    }
    __syncthreads();

    // coalesced-run write out
    #pragma unroll
    for (int j = 0; j < 4; ++j) {
        int i = j * 1024 + t;
        if (i < n) {
            int bu = sbkt[i];
            int gp = gstart[bu] + (i - sexcl[bu]);
            if (gp < kBktCap) bin[(size_t)bu * kBktCap + gp] = staged[i];
        }
    }
}

// ---------------- exclusive scan over bucket sizes ----------------

__global__ __launch_bounds__(1024) void scan_base_kernel(const int* __restrict__ cur,
                                                         int* __restrict__ base) {
    __shared__ int wsum[16];
    int t = threadIdx.x;
    int lane = t & 63, w = t >> 6;
    int v = (t < kBkt) ? min(cur[t], kBktCap) : 0;
    int inc = wave_incl_scan(v, lane);
    if (lane == 63) wsum[w] = inc;
    __syncthreads();
    if (w == 0) {
        int x  = (lane < 16) ? wsum[lane] : 0;
        int sc = wave_incl_scan(x, lane);
        if (lane < 16) wsum[lane] = sc - x;
    }
    __syncthreads();
    if (t < kBkt) base[t] = wsum[w] + inc - v;
}

// ---------------- Phase B: per-bucket CSR build + offcnt/dinv + prescale ----------------

__global__ __launch_bounds__(256) void binB_kernel(const int* __restrict__ cur,
                                                   const int* __restrict__ base,
                                                   const unsigned* __restrict__ bin,
                                                   int* __restrict__ pairs,
                                                   int2* __restrict__ offcnt,
                                                   float* __restrict__ dinv,
                                                   const float4* __restrict__ emb4,
                                                   int4* __restrict__ y4) {
    __shared__ int lcnt[256];
    __shared__ int cursor[256];
    __shared__ int wsum[4];
    __shared__ int stage[kBktCap];
    __shared__ float sdinv[256];

    int b = blockIdx.x;
    int t = threadIdx.x;
    int lane = t & 63, w = t >> 6;
    int cnt = min(cur[b], kBktCap);
    int bs  = base[b];
    const unsigned* mybin = bin + (size_t)b * kBktCap;

    lcnt[t] = 0;
    __syncthreads();
    for (int i = t; i < cnt; i += 256) atomicAdd(&lcnt[mybin[i] >> 24], 1);
    __syncthreads();

    int c   = lcnt[t];
    int inc = wave_incl_scan(c, lane);
    if (lane == 63) wsum[w] = inc;
    __syncthreads();
    if (t == 0) {
        int a = 0;
        #pragma unroll
        for (int k = 0; k < 4; ++k) { int v = wsum[k]; wsum[k] = a; a += v; }
    }
    __syncthreads();
    int excl = wsum[w] + inc - c;

    int node = (b << 8) + t;
    float dv = (c > 0) ? rsqrtf((float)c) : 0.0f;
    sdinv[t] = dv;
    if (node < kNodes) {
        offcnt[node] = make_int2(bs + excl, c);
        dinv[node]   = dv;
    }
    cursor[t] = excl;
    __syncthreads();

    for (int i = t; i < cnt; i += 256) {
        unsigned v = mybin[i];
        int p = atomicAdd(&cursor[v >> 24], 1);
        stage[p] = (int)(v & 0x00FFFFFFu);
    }
    __syncthreads();
    for (int i = t; i < cnt; i += 256) pairs[bs + i] = stage[i];

    // fused prescale: y0 = fp16(emb * dinv) for this bucket's 256 nodes.
    // 2048 int4 rows-chunks per bucket; idx = (node_local<<3) | q, contiguous.
    // node kNodes gets an all-zeros row (padding target for gather's dummy loads).
    #pragma unroll
    for (int k = 0; k < 8; ++k) {
        int idx   = (k << 8) + t;
        int nl    = idx >> 3;
        int node2 = (b << 8) + nl;
        int qq    = idx & 7;
        if (node2 < kNodes) {
            float d = sdinv[nl];
            size_t e = (size_t)node2 * 16 + (size_t)qq * 2;
            float4 v0 = emb4[e];
            float4 v1 = emb4[e + 1];
            __half2 p0 = __floats2half2_rn(v0.x * d, v0.y * d);
            __half2 p1 = __floats2half2_rn(v0.z * d, v0.w * d);
            __half2 p2 = __floats2half2_rn(v1.x * d, v1.y * d);
            __half2 p3 = __floats2half2_rn(v1.z * d, v1.w * d);
            int4 wv;
            wv.x = *reinterpret_cast<int*>(&p0); wv.y = *reinterpret_cast<int*>(&p1);
            wv.z = *reinterpret_cast<int*>(&p2); wv.w = *reinterpret_cast<int*>(&p3);
            y4[(size_t)node2 * 8 + qq] = wv;
        } else if (node2 == kNodes) {
            int4 z; z.x = 0; z.y = 0; z.z = 0; z.w = 0;
            y4[(size_t)node2 * 8 + qq] = z;
        }
    }
}

// ---------------- gather layer v3: 8 lanes per node, 8 nodes per wave ----------------
// lane = g*8 + q : g = node sub-group (0..7), q = 16B chunk (8 dims) of the row.
// Per 8-edge block: all 8 row loads issued back-to-back (dummy slots -> zero
// row at index kNodes), then 64 unconditional v_fma_mix accumulates.
// mode 0: yOut = fp16(dinv^2 * s)              (layers 1,2)
// mode 1: out = (emb + (y1+y2)*sqrt(cnt) + dinv*s) * 0.25   (layer 3)

__global__ __launch_bounds__(256) void gather_kernel(const int2* __restrict__ offcnt,
                                                     const int* __restrict__ pairs,
                                                     const __half* __restrict__ x16,
                                                     const float* __restrict__ dinv,
                                                     __half* __restrict__ yOut,
                                                     const float4* __restrict__ emb4,
                                                     const __half* __restrict__ y1,
                                                     const __half* __restrict__ y2,
                                                     float* __restrict__ outf,
                                                     int mode) {
    int t    = blockIdx.x * 256 + threadIdx.x;
    int node = t >> 3;
    if (node > kNodes) return;
    int q    = t & 7;
    if (node == kNodes) {
        // maintain the zero row in the NEXT layer's x-table
        if (mode == 0) {
            int4 z; z.x = 0; z.y = 0; z.z = 0; z.w = 0;
            ((int4*)(yOut + ((size_t)node << 6)))[q] = z;
        }
        return;
    }
    int lane = threadIdx.x & 63;
    int gb   = lane & 56;                 // first lane of my group

    int2 oc = offcnt[node];
    int b = oc.x, cnt = oc.y;

    float s0 = 0.f, s1 = 0.f, s2 = 0.f, s3 = 0.f,
          s4 = 0.f, s5 = 0.f, s6 = 0.f, s7 = 0.f;

    // lane q holds edge (base+q)'s src; broadcast within group via shfl.
    // OOB slots hold kNodes -> zero row, so the 8-block is branchless.
    int mysrc = (q < cnt) ? pairs[b + q] : kNodes;
    for (int base2 = 0; base2 < cnt; base2 += 8) {
        int np  = base2 + 8 + q;
        int nxt = (np < cnt) ? pairs[b + np] : kNodes;   // prefetch next block

        int si0 = __shfl(mysrc, gb + 0);
        int si1 = __shfl(mysrc, gb + 1);
        int si2 = __shfl(mysrc, gb + 2);
        int si3 = __shfl(mysrc, gb + 3);
        int si4 = __shfl(mysrc, gb + 4);
        int si5 = __shfl(mysrc, gb + 5);
        int si6 = __shfl(mysrc, gb + 6);
        int si7 = __shfl(mysrc, gb + 7);
        int4 r0 = *(const int4*)(x16 + ((size_t)si0 << 6) + (q << 3));
        int4 r1 = *(const int4*)(x16 + ((size_t)si1 << 6) + (q << 3));
        int4 r2 = *(const int4*)(x16 + ((size_t)si2 << 6) + (q << 3));
        int4 r3 = *(const int4*)(x16 + ((size_t)si3 << 6) + (q << 3));
        int4 r4 = *(const int4*)(x16 + ((size_t)si4 << 6) + (q << 3));
        int4 r5 = *(const int4*)(x16 + ((size_t)si5 << 6) + (q << 3));
        int4 r6 = *(const int4*)(x16 + ((size_t)si6 << 6) + (q << 3));
        int4 r7 = *(const int4*)(x16 + ((size_t)si7 << 6) + (q << 3));
        ACC_ROW(r0); ACC_ROW(r1); ACC_ROW(r2); ACC_ROW(r3);
        ACC_ROW(r4); ACC_ROW(r5); ACC_ROW(r6); ACC_ROW(r7);
        mysrc = nxt;
    }

    float dv = dinv[node];
    if (mode == 0) {
        float dv2 = dv * dv;
        __half2 p0 = __floats2half2_rn(s0 * dv2, s1 * dv2);
        __half2 p1 = __floats2half2_rn(s2 * dv2, s3 * dv2);
        __half2 p2 = __floats2half2_rn(s4 * dv2, s5 * dv2);
        __half2 p3 = __floats2half2_rn(s6 * dv2, s7 * dv2);
        int4 wv;
        wv.x = *reinterpret_cast<int*>(&p0); wv.y = *reinterpret_cast<int*>(&p1);
        wv.z = *reinterpret_cast<int*>(&p2); wv.w = *reinterpret_cast<int*>(&p3);
        ((int4*)(yOut + ((size_t)node << 6)))[q] = wv;
    } else {
        float sq = sqrtf((float)cnt);        // = 1/dinv (0 if deg 0)
        size_t i4 = (size_t)node * 16 + (size_t)q * 2;
        int4 r1 = ((const int4*)(y1 + ((size_t)node << 6)))[q];
        int4 r2 = ((const int4*)(y2 + ((size_t)node << 6)))[q];
        float4 e0 = emb4[i4];
        float4 e1 = emb4[i4 + 1];
        float2 a0 = __half22float2(*reinterpret_cast<__half2*>(&r1.x));
        float2 a1 = __half22float2(*reinterpret_cast<__half2*>(&r1.y));
        float2 a2 = __half22float2(*reinterpret_cast<__half2*>(&r1.z));
        float2 a3 = __half22float2(*reinterpret_cast<__half2*>(&r1.w));
        float2 c0 = __half22float2(*reinterpret_cast<__half2*>(&r2.x));
        float2 c1 = __half22float2(*reinterpret_cast<__half2*>(&r2.y));
        float2 c2 = __half22float2(*reinterpret_cast<__half2*>(&r2.z));
        float2 c3 = __half22float2(*reinterpret_cast<__half2*>(&r2.w));
        floatx4 o0, o1;
        o0.x = (e0.x + (a0.x + c0.x) * sq + s0 * dv) * 0.25f;
        o0.y = (e0.y + (a0.y + c0.y) * sq + s1 * dv) * 0.25f;
        o0.z = (e0.z + (a1.x + c1.x) * sq + s2 * dv) * 0.25f;
        o0.w = (e0.w + (a1.y + c1.y) * sq + s3 * dv) * 0.25f;
        o1.x = (e1.x + (a2.x + c2.x) * sq + s4 * dv) * 0.25f;
        o1.y = (e1.y + (a2.y + c2.y) * sq + s5 * dv) * 0.25f;
        o1.z = (e1.z + (a3.x + c3.x) * sq + s6 * dv) * 0.25f;
        o1.w = (e1.w + (a3.y + c3.y) * sq + s7 * dv) * 0.25f;
        floatx4* op = (floatx4*)(outf + i4 * 4);
        __builtin_nontemporal_store(o0, op);
        __builtin_nontemporal_store(o1, op + 1);
    }
}

// ---------------- launch ----------------

extern "C" void kernel_launch(void* const* d_in, const int* in_sizes, int n_in,
                              void* d_out, int out_size, void* d_ws, size_t ws_size,
                              hipStream_t stream) {
    const int*   edge  = (const int*)d_in[0];
    const int*   src   = edge;
    const int*   dst   = edge + kEdges;
    const float* emb_w = (const float*)d_in[1];
    float*       out   = (float*)d_out;

    // Workspace layout (re-poisoned 0xAA each call):
    //   cur     : @0          4096
    //   binBase : @4096       4096
    //   offcnt  : @8192       1,200,000 (int2 per node)
    //   dinv    : @1208192    600,000
    //   pairs   : @1808192    4,000,000
    //   bin     : @5808192    586*2048*4 = 4,800,512
    //   y0      : @10608704   19,200,128  (150001 rows: last is the zero row)
    //   yA      : @29808832   19,200,128
    //   yB      : @49008960   19,200,128  (end ~68.2 MB)
    char*     ws      = (char*)d_ws;
    int*      cur     = (int*)(ws);
    int*      binBase = (int*)(ws + 4096);
    int2*     offcnt  = (int2*)(ws + 8192);
    float*    dinv    = (float*)(ws + 1208192);
    int*      pairs   = (int*)(ws + 1808192);
    unsigned* bin     = (unsigned*)(ws + 5808192);
    __half*   y0      = (__half*)(ws + 10608704);
    __half*   yA      = (__half*)(ws + 29808832);
    __half*   yB      = (__half*)(ws + 49008960);

    const int binABlocks   = (kEdges + kChunk - 1) / kChunk;   // 245
    const int gatherBlocks = ((kNodes + 1) * 8 + 255) / 256;   // 4688

    (void)hipMemsetAsync(cur, 0, (size_t)kBkt * 4, stream);
    binA_kernel<<<binABlocks, 1024, 0, stream>>>(src, dst, cur, bin);
    scan_base_kernel<<<1, 1024, 0, stream>>>(cur, binBase);
    binB_kernel<<<kBkt, 256, 0, stream>>>(cur, binBase, bin, pairs, offcnt, dinv,
                                          (const float4*)emb_w, (int4*)y0);

    // Layer 1: yA = fp16(dinv^2 * sum y0[src])
    gather_kernel<<<gatherBlocks, 256, 0, stream>>>(offcnt, pairs, y0, dinv,
                                                    yA, nullptr, nullptr, nullptr,
                                                    nullptr, 0);
    // Layer 2: yB = fp16(dinv^2 * sum yA[src])
    gather_kernel<<<gatherBlocks, 256, 0, stream>>>(offcnt, pairs, yA, dinv,
                                                    yB, nullptr, nullptr, nullptr,
                                                    nullptr, 0);
    // Layer 3: out = (emb + h1 + h2 + h3)/4
    gather_kernel<<<gatherBlocks, 256, 0, stream>>>(offcnt, pairs, yB, dinv,
                                                    nullptr, (const float4*)emb_w,
                                                    yA, yB, out, 1);
}

// Round 4
// 218.387 us; speedup vs baseline: 1.0732x; 1.0732x over previous
//
#include <hip/hip_runtime.h>
#include <hip/hip_fp16.h>

// LightGCN on MI355X. Gather formulation, dinv folded into data (y = dinv*x,
// fp16 128B rows). CSR built via LDS-staged two-phase binning (wave-scan based).
// Gather v4: 8 lanes per node, 8 nodes per wave, branchless 8-edge blocks
// (zero row at index kNodes pads OOB slots). Nodes are processed in per-bucket
// DEGREE-SORTED order (order[] permutation built in binB via counting sort) so
// the 8 nodes of a wave have ~equal degree -> minimal dummy loads, no straggler
// waves. dinv is derived from cnt in-kernel (no dinv array). scan_base is fused
// into binB as a per-block reduction (one fewer serial dispatch).
// Layers 1-2 write only y (19.2MB). Layer 3 reconstructs h1,h2 from y1,y2
// (h = y * sqrt(deg)) and writes out = (emb + h1 + h2 + h3)/4.
// prescale (y0 = fp16(dinv*emb)) is fused into the tail of binB.
//
// d_in[0]: edge_index int32 [2][1M]; d_in[1]: emb_weight fp32 [150000][64]
// d_out  : 150000x64 fp32

constexpr int kNodes     = 150000;
constexpr int kDim       = 64;
constexpr int kEdges     = 1000000;
constexpr int kEmbFloats = kNodes * kDim;            // 9,600,000
constexpr int kBkt       = (kNodes + 255) / 256;     // 586 buckets
constexpr int kBktCap    = 2048;                     // mean 1707, +8.3 sigma
constexpr int kChunk     = 4096;                     // edges per binA block

typedef float  floatx4 __attribute__((ext_vector_type(4)));

__device__ __forceinline__ int wave_incl_scan(int v, int lane) {
    #pragma unroll
    for (int s = 1; s < 64; s <<= 1) {
        int u = __shfl_up(v, s);
        if (lane >= s) v += u;
    }
    return v;
}

// fp16 (packed in int bits) accumulated into fp32 in one VALU op.
#define ACC_LO(s, r) asm("v_fma_mix_f32 %0, %1, 1.0, %0 op_sel:[0,0,0] op_sel_hi:[1,0,0]" : "+v"(s) : "v"(r))
#define ACC_HI(s, r) asm("v_fma_mix_f32 %0, %1, 1.0, %0 op_sel:[1,0,0] op_sel_hi:[1,0,0]" : "+v"(s) : "v"(r))

#define ACC_ROW(rr) do { \
    ACC_LO(s0, rr.x); ACC_HI(s1, rr.x); \
    ACC_LO(s2, rr.y); ACC_HI(s3, rr.y); \
    ACC_LO(s4, rr.z); ACC_HI(s5, rr.z); \
    ACC_LO(s6, rr.w); ACC_HI(s7, rr.w); } while (0)

// ---------------- Phase A: bin edges by dst>>8, LDS-staged ----------------

__global__ __launch_bounds__(1024) void binA_kernel(const int* __restrict__ src,
                                                    const int* __restrict__ dst,
                                                    int* __restrict__ cur,     // [kBkt] zeroed
                                                    unsigned* __restrict__ bin) {
    __shared__ int hist[1024];
    __shared__ int cursor[1024];
    __shared__ int sexcl[1024];
    __shared__ int gstart[1024];
    __shared__ int wsum[16];
    __shared__ unsigned staged[kChunk];
    __shared__ unsigned short sbkt[kChunk];

    int t      = threadIdx.x;
    int lane   = t & 63;
    int w      = t >> 6;
    int chunk0 = blockIdx.x * kChunk;
    int n      = min(kChunk, kEdges - chunk0);

    hist[t] = 0;
    __syncthreads();

    int myb[4], myd[4];
    #pragma unroll
    for (int j = 0; j < 4; ++j) {
        int i = j * 1024 + t;
        if (i < n) {
            int d = dst[chunk0 + i];
            myb[j] = d >> 8;
            myd[j] = d & 255;
            atomicAdd(&hist[myb[j]], 1);
        } else myb[j] = -1;
    }
    __syncthreads();

    // exclusive scan of hist[0..1023] via wave scans
    int c   = hist[t];
    int inc = wave_incl_scan(c, lane);
    if (lane == 63) wsum[w] = inc;
    __syncthreads();
    if (w == 0) {
        int v  = (lane < 16) ? wsum[lane] : 0;
        int sc = wave_incl_scan(v, lane);
        if (lane < 16) wsum[lane] = sc - v;   // exclusive wave offsets
    }
    __syncthreads();
    int excl = wsum[w] + inc - c;
    sexcl[t]  = excl;
    cursor[t] = excl;
    if (t < kBkt) gstart[t] = atomicAdd(&cur[t], c);
    __syncthreads();

    // place into LDS ordered by bucket
    #pragma unroll
    for (int j = 0; j < 4; ++j) {
        int i = j * 1024 + t;
        if (i < n) {
            int s = src[chunk0 + i];
            unsigned pk = ((unsigned)myd[j] << 24) | (unsigned)s;
            int p = atomicAdd(&cursor[myb[j]], 1);
            staged[p] = pk;
            sbkt[p]   = (unsigned short)myb[j];
        }
    }
    __syncthreads();

    // coalesced-run write out
    #pragma unroll
    for (int j = 0; j < 4; ++j) {
        int i = j * 1024 + t;
        if (i < n) {
            int bu = sbkt[i];
            int gp = gstart[bu] + (i - sexcl[bu]);
            if (gp < kBktCap) bin[(size_t)bu * kBktCap + gp] = staged[i];
        }
    }
}

// ---------------- Phase B: per-bucket CSR build + offcnt + degree-sort + prescale ----
// Fuses: (a) base = prefix over bucket sizes (per-block reduction over cur[]),
// (b) per-node offset/count, (c) counting sort of the bucket's 256 nodes by
// degree -> order[] permutation, (d) prescale y0 = fp16(emb*dinv).

__global__ __launch_bounds__(256) void binB_kernel(const int* __restrict__ cur,
                                                   const unsigned* __restrict__ bin,
                                                   int* __restrict__ pairs,
                                                   int2* __restrict__ offcnt,
                                                   int* __restrict__ order,
                                                   const float4* __restrict__ emb4,
                                                   int4* __restrict__ y4) {
    __shared__ int lcnt[256];
    __shared__ int cursor[256];
    __shared__ int wsum[4];
    __shared__ int wred[4];
    __shared__ int chist[64];
    __shared__ int stage[kBktCap];
    __shared__ float sdinv[256];

    int b = blockIdx.x;
    int t = threadIdx.x;
    int lane = t & 63, w = t >> 6;
    int cnt = min(cur[b], kBktCap);
    const unsigned* mybin = bin + (size_t)b * kBktCap;

    // fused scan_base: bs = sum_{j<b} min(cur[j], cap)
    {
        int acc = 0;
        for (int j = t; j < b; j += 256) acc += min(cur[j], kBktCap);
        #pragma unroll
        for (int s = 32; s; s >>= 1) acc += __shfl_down(acc, s);
        if (lane == 0) wred[w] = acc;
    }

    lcnt[t] = 0;
    if (t < 64) chist[t] = 0;
    __syncthreads();
    int bs = wred[0] + wred[1] + wred[2] + wred[3];

    for (int i = t; i < cnt; i += 256) atomicAdd(&lcnt[mybin[i] >> 24], 1);
    __syncthreads();

    int c   = lcnt[t];
    int inc = wave_incl_scan(c, lane);
    if (lane == 63) wsum[w] = inc;
    int cv = min(c, 63);
    atomicAdd(&chist[cv], 1);
    __syncthreads();

    if (t < 64) {
        int v  = chist[t];
        int sc = wave_incl_scan(v, lane);
        chist[t] = sc - v;                 // exclusive start -> becomes cursor
    }
    if (t == 0) {
        int a = 0;
        #pragma unroll
        for (int k = 0; k < 4; ++k) { int v = wsum[k]; wsum[k] = a; a += v; }
    }
    __syncthreads();
    int excl = wsum[w] + inc - c;

    int node = (b << 8) + t;
    float dv = (c > 0) ? rsqrtf((float)c) : 0.0f;
    sdinv[t] = dv;
    if (node < kNodes) offcnt[node] = make_int2(bs + excl, c);
    cursor[t] = excl;

    // counting-sort placement: degree-sorted order within the bucket
    {
        int slot = atomicAdd(&chist[cv], 1);
        order[(b << 8) + slot] = (node < kNodes) ? node : kNodes;
    }
    __syncthreads();

    for (int i = t; i < cnt; i += 256) {
        unsigned v = mybin[i];
        int p = atomicAdd(&cursor[v >> 24], 1);
        stage[p] = (int)(v & 0x00FFFFFFu);
    }
    __syncthreads();
    for (int i = t; i < cnt; i += 256) pairs[bs + i] = stage[i];

    // fused prescale: y0 = fp16(emb * dinv) for this bucket's 256 nodes.
    // node kNodes gets an all-zeros row (padding target for gather's dummy loads).
    #pragma unroll
    for (int k = 0; k < 8; ++k) {
        int idx   = (k << 8) + t;
        int nl    = idx >> 3;
        int node2 = (b << 8) + nl;
        int qq    = idx & 7;
        if (node2 < kNodes) {
            float d = sdinv[nl];
            size_t e = (size_t)node2 * 16 + (size_t)qq * 2;
            float4 v0 = emb4[e];
            float4 v1 = emb4[e + 1];
            __half2 p0 = __floats2half2_rn(v0.x * d, v0.y * d);
            __half2 p1 = __floats2half2_rn(v0.z * d, v0.w * d);
            __half2 p2 = __floats2half2_rn(v1.x * d, v1.y * d);
            __half2 p3 = __floats2half2_rn(v1.z * d, v1.w * d);
            int4 wv;
            wv.x = *reinterpret_cast<int*>(&p0); wv.y = *reinterpret_cast<int*>(&p1);
            wv.z = *reinterpret_cast<int*>(&p2); wv.w = *reinterpret_cast<int*>(&p3);
            y4[(size_t)node2 * 8 + qq] = wv;
        } else if (node2 == kNodes) {
            int4 z; z.x = 0; z.y = 0; z.z = 0; z.w = 0;
            y4[(size_t)node2 * 8 + qq] = z;
        }
    }
}

// ---------------- gather layer v4: degree-sorted, 8 lanes/node, 8 nodes/wave --------
// slot = t>>3 indexes order[] (degree-sorted permutation); node = order[slot].
// Per 8-edge block: all 8 row loads issued back-to-back (dummy slots -> zero
// row at index kNodes), then 64 unconditional v_fma_mix accumulates.
// dv derived from cnt (no dinv array).
// mode 0: yOut = fp16(dinv^2 * s)              (layers 1,2)
// mode 1: out = (emb + (y1+y2)*sqrt(cnt) + dinv*s) * 0.25   (layer 3)

__global__ __launch_bounds__(256) void gather_kernel(const int2* __restrict__ offcnt,
                                                     const int* __restrict__ order,
                                                     const int* __restrict__ pairs,
                                                     const __half* __restrict__ x16,
                                                     __half* __restrict__ yOut,
                                                     const float4* __restrict__ emb4,
                                                     const __half* __restrict__ y1,
                                                     const __half* __restrict__ y2,
                                                     float* __restrict__ outf,
                                                     int mode) {
    int t    = blockIdx.x * 256 + threadIdx.x;
    int slot = t >> 3;                    // 0 .. kBkt*256-1 = 150015
    int q    = t & 7;
    int node = order[slot];
    if (node == kNodes) {
        // maintain the zero row in the NEXT layer's x-table (redundant writes ok)
        if (mode == 0) {
            int4 z; z.x = 0; z.y = 0; z.z = 0; z.w = 0;
            ((int4*)(yOut + ((size_t)kNodes << 6)))[q] = z;
        }
        return;
    }
    int lane = threadIdx.x & 63;
    int gb   = lane & 56;                 // first lane of my group

    int2 oc = offcnt[node];
    int b = oc.x, cnt = oc.y;

    float s0 = 0.f, s1 = 0.f, s2 = 0.f, s3 = 0.f,
          s4 = 0.f, s5 = 0.f, s6 = 0.f, s7 = 0.f;

    // lane q holds edge (base+q)'s src; broadcast within group via shfl.
    // OOB slots hold kNodes -> zero row, so the 8-block is branchless.
    int mysrc = (q < cnt) ? pairs[b + q] : kNodes;
    for (int base2 = 0; base2 < cnt; base2 += 8) {
        int np  = base2 + 8 + q;
        int nxt = (np < cnt) ? pairs[b + np] : kNodes;   // prefetch next block

        int si0 = __shfl(mysrc, gb + 0);
        int si1 = __shfl(mysrc, gb + 1);
        int si2 = __shfl(mysrc, gb + 2);
        int si3 = __shfl(mysrc, gb + 3);
        int si4 = __shfl(mysrc, gb + 4);
        int si5 = __shfl(mysrc, gb + 5);
        int si6 = __shfl(mysrc, gb + 6);
        int si7 = __shfl(mysrc, gb + 7);
        int4 r0 = *(const int4*)(x16 + ((size_t)si0 << 6) + (q << 3));
        int4 r1 = *(const int4*)(x16 + ((size_t)si1 << 6) + (q << 3));
        int4 r2 = *(const int4*)(x16 + ((size_t)si2 << 6) + (q << 3));
        int4 r3 = *(const int4*)(x16 + ((size_t)si3 << 6) + (q << 3));
        int4 r4 = *(const int4*)(x16 + ((size_t)si4 << 6) + (q << 3));
        int4 r5 = *(const int4*)(x16 + ((size_t)si5 << 6) + (q << 3));
        int4 r6 = *(const int4*)(x16 + ((size_t)si6 << 6) + (q << 3));
        int4 r7 = *(const int4*)(x16 + ((size_t)si7 << 6) + (q << 3));
        ACC_ROW(r0); ACC_ROW(r1); ACC_ROW(r2); ACC_ROW(r3);
        ACC_ROW(r4); ACC_ROW(r5); ACC_ROW(r6); ACC_ROW(r7);
        mysrc = nxt;
    }

    float dv = (cnt > 0) ? rsqrtf((float)cnt) : 0.0f;
    if (mode == 0) {
        float dv2 = dv * dv;
        __half2 p0 = __floats2half2_rn(s0 * dv2, s1 * dv2);
        __half2 p1 = __floats2half2_rn(s2 * dv2, s3 * dv2);
        __half2 p2 = __floats2half2_rn(s4 * dv2, s5 * dv2);
        __half2 p3 = __floats2half2_rn(s6 * dv2, s7 * dv2);
        int4 wv;
        wv.x = *reinterpret_cast<int*>(&p0); wv.y = *reinterpret_cast<int*>(&p1);
        wv.z = *reinterpret_cast<int*>(&p2); wv.w = *reinterpret_cast<int*>(&p3);
        ((int4*)(yOut + ((size_t)node << 6)))[q] = wv;
    } else {
        float sq = sqrtf((float)cnt);        // = 1/dinv (0 if deg 0)
        size_t i4 = (size_t)node * 16 + (size_t)q * 2;
        int4 r1 = ((const int4*)(y1 + ((size_t)node << 6)))[q];
        int4 r2 = ((const int4*)(y2 + ((size_t)node << 6)))[q];
        float4 e0 = emb4[i4];
        float4 e1 = emb4[i4 + 1];
        float2 a0 = __half22float2(*reinterpret_cast<__half2*>(&r1.x));
        float2 a1 = __half22float2(*reinterpret_cast<__half2*>(&r1.y));
        float2 a2 = __half22float2(*reinterpret_cast<__half2*>(&r1.z));
        float2 a3 = __half22float2(*reinterpret_cast<__half2*>(&r1.w));
        float2 c0 = __half22float2(*reinterpret_cast<__half2*>(&r2.x));
        float2 c1 = __half22float2(*reinterpret_cast<__half2*>(&r2.y));
        float2 c2 = __half22float2(*reinterpret_cast<__half2*>(&r2.z));
        float2 c3 = __half22float2(*reinterpret_cast<__half2*>(&r2.w));
        floatx4 o0, o1;
        o0.x = (e0.x + (a0.x + c0.x) * sq + s0 * dv) * 0.25f;
        o0.y = (e0.y + (a0.y + c0.y) * sq + s1 * dv) * 0.25f;
        o0.z = (e0.z + (a1.x + c1.x) * sq + s2 * dv) * 0.25f;
        o0.w = (e0.w + (a1.y + c1.y) * sq + s3 * dv) * 0.25f;
        o1.x = (e1.x + (a2.x + c2.x) * sq + s4 * dv) * 0.25f;
        o1.y = (e1.y + (a2.y + c2.y) * sq + s5 * dv) * 0.25f;
        o1.z = (e1.z + (a3.x + c3.x) * sq + s6 * dv) * 0.25f;
        o1.w = (e1.w + (a3.y + c3.y) * sq + s7 * dv) * 0.25f;
        floatx4* op = (floatx4*)(outf + i4 * 4);
        __builtin_nontemporal_store(o0, op);
        __builtin_nontemporal_store(o1, op + 1);
    }
}

// ---------------- launch ----------------

extern "C" void kernel_launch(void* const* d_in, const int* in_sizes, int n_in,
                              void* d_out, int out_size, void* d_ws, size_t ws_size,
                              hipStream_t stream) {
    const int*   edge  = (const int*)d_in[0];
    const int*   src   = edge;
    const int*   dst   = edge + kEdges;
    const float* emb_w = (const float*)d_in[1];
    float*       out   = (float*)d_out;

    // Workspace layout (re-poisoned 0xAA each call):
    //   cur     : @0          4096
    //   order   : @4096       600,064 (kBkt*256 ints, degree-sorted permutation)
    //   offcnt  : @604160     1,200,000 (int2 per node)
    //   pairs   : @1804160    4,000,000
    //   bin     : @5804160    586*2048*4 = 4,800,512
    //   y0      : @10604672   19,200,128  (150001 rows: last is the zero row)
    //   yA      : @29804800   19,200,128
    //   yB      : @49004928   19,200,128  (end ~68.2 MB)
    char*     ws      = (char*)d_ws;
    int*      cur     = (int*)(ws);
    int*      order   = (int*)(ws + 4096);
    int2*     offcnt  = (int2*)(ws + 604160);
    int*      pairs   = (int*)(ws + 1804160);
    unsigned* bin     = (unsigned*)(ws + 5804160);
    __half*   y0      = (__half*)(ws + 10604672);
    __half*   yA      = (__half*)(ws + 29804800);
    __half*   yB      = (__half*)(ws + 49004928);

    const int binABlocks   = (kEdges + kChunk - 1) / kChunk;   // 245
    const int gatherBlocks = (kBkt * 256 * 8) / 256;           // 4688, exact

    (void)hipMemsetAsync(cur, 0, (size_t)kBkt * 4, stream);
    binA_kernel<<<binABlocks, 1024, 0, stream>>>(src, dst, cur, bin);
    binB_kernel<<<kBkt, 256, 0, stream>>>(cur, bin, pairs, offcnt, order,
                                          (const float4*)emb_w, (int4*)y0);

    // Layer 1: yA = fp16(dinv^2 * sum y0[src])
    gather_kernel<<<gatherBlocks, 256, 0, stream>>>(offcnt, order, pairs, y0,
                                                    yA, nullptr, nullptr, nullptr,
                                                    nullptr, 0);
    // Layer 2: yB = fp16(dinv^2 * sum yA[src])
    gather_kernel<<<gatherBlocks, 256, 0, stream>>>(offcnt, order, pairs, yA,
                                                    yB, nullptr, nullptr, nullptr,
                                                    nullptr, 0);
    // Layer 3: out = (emb + h1 + h2 + h3)/4
    gather_kernel<<<gatherBlocks, 256, 0, stream>>>(offcnt, order, pairs, yB,
                                                    nullptr, (const float4*)emb_w,
                                                    yA, yB, out, 1);
}